// Round 1
// baseline (341.668 us; speedup 1.0000x reference)
//
#include <hip/hip_runtime.h>
#include <cstdint>
#include <cstddef>

// BitLinear inference, round 1: correctness-first m97-style bf16 MFMA GEMM.
// x_q/w_q are small integers -> exactly representable in bf16 -> f32-accum
// MFMA is bit-exact integer math.
//
// ws layout (bytes):
//   [0      .. 16)        red[4] = {sum_w, sumabs_w, sum_b, sumabs_b}
//   [1024   .. 132096)    x_scale[32768] f32
//   [132096 .. 2229248)   w_q bf16 bits [1024*1024] (ushort)
//   [2229248.. 69338112)  x_q bf16 bits [32768*1024] (ushort)

typedef __attribute__((ext_vector_type(8))) short short8;
typedef __attribute__((ext_vector_type(4))) float f32x4;

static constexpr int DIM = 1024;    // inner dim K
static constexpr int OUTF = 1024;   // output features N
static constexpr int MROWS = 32768; // B*S
static constexpr float INV_WN = 1.0f / (1024.0f * 1024.0f);
static constexpr float INV_BN = 1.0f / 1024.0f;

#define OFF_XSCALE 1024
#define OFF_WQ 132096
#define OFF_XQ 2229248

__device__ inline float wave_sum(float v) {
#pragma unroll
  for (int off = 32; off; off >>= 1) v += __shfl_down(v, off);
  return v;
}
__device__ inline float wave_max(float v) {
#pragma unroll
  for (int off = 32; off; off >>= 1) v = fmaxf(v, __shfl_down(v, off));
  return v;
}

// bf16 bits of a float that is exactly representable in bf16 (small ints)
__device__ inline unsigned short f32_to_bf16_exact(float f) {
  return (unsigned short)(__float_as_uint(f) >> 16);
}

// ---------------------------------------------------------------- reductions
__global__ __launch_bounds__(256) void reduce_wb(const float* __restrict__ w,
                                                 const float* __restrict__ b,
                                                 float* __restrict__ red) {
  __shared__ float ss[4], sa[4];
  const int t = threadIdx.x;
  const int lane = t & 63, wv = t >> 6;
  float s = 0.0f, a = 0.0f;
  const float4* w4 = (const float4*)w;
  const int idx = blockIdx.x * 256 + t;
#pragma unroll
  for (int i = 0; i < 4; ++i) {
    float4 v = w4[idx + i * 65536];
    s += (v.x + v.y) + (v.z + v.w);
    a += (fabsf(v.x) + fabsf(v.y)) + (fabsf(v.z) + fabsf(v.w));
  }
  s = wave_sum(s);
  a = wave_sum(a);
  if (lane == 0) { ss[wv] = s; sa[wv] = a; }
  __syncthreads();
  if (t == 0) atomicAdd(&red[0], (ss[0] + ss[1]) + (ss[2] + ss[3]));
  if (t == 1) atomicAdd(&red[1], (sa[0] + sa[1]) + (sa[2] + sa[3]));
  if (blockIdx.x == 0) {
    __syncthreads();  // block-uniform branch, safe
    float4 v = ((const float4*)b)[t];
    float s2 = (v.x + v.y) + (v.z + v.w);
    float a2 = (fabsf(v.x) + fabsf(v.y)) + (fabsf(v.z) + fabsf(v.w));
    s2 = wave_sum(s2);
    a2 = wave_sum(a2);
    if (lane == 0) { ss[wv] = s2; sa[wv] = a2; }
    __syncthreads();
    if (t == 0) {
      red[2] = (ss[0] + ss[1]) + (ss[2] + ss[3]);
      red[3] = (sa[0] + sa[1]) + (sa[2] + sa[3]);
    }
  }
}

// ---------------------------------------------------------------- weight quant
__global__ __launch_bounds__(256) void quant_w(const float* __restrict__ w,
                                               const float* __restrict__ red,
                                               unsigned short* __restrict__ wq) {
  const float wmean = red[0] * INV_WN;
  const int idx = blockIdx.x * 256 + threadIdx.x;
  float4 v = ((const float4*)w)[idx];
  ushort4 pk;
  float d;
  d = v.x - wmean; pk.x = d > 0.f ? 0x3F80u : (d < 0.f ? 0xBF80u : 0u);
  d = v.y - wmean; pk.y = d > 0.f ? 0x3F80u : (d < 0.f ? 0xBF80u : 0u);
  d = v.z - wmean; pk.z = d > 0.f ? 0x3F80u : (d < 0.f ? 0xBF80u : 0u);
  d = v.w - wmean; pk.w = d > 0.f ? 0x3F80u : (d < 0.f ? 0xBF80u : 0u);
  ((ushort4*)wq)[idx] = pk;
}

// ---------------------------------------------------------------- activation quant
__global__ __launch_bounds__(256) void quant_x(const float* __restrict__ x,
                                               unsigned short* __restrict__ xq,
                                               float* __restrict__ xscale) {
  const int row = blockIdx.x;
  const int t = threadIdx.x;
  const int lane = t & 63, wv = t >> 6;
  __shared__ float sss[4], sma[4];

  float4 v = ((const float4*)(x + (size_t)row * DIM))[t];
  float ss = v.x * v.x + v.y * v.y + v.z * v.z + v.w * v.w;
  float ma = fmaxf(fmaxf(fabsf(v.x), fabsf(v.y)), fmaxf(fabsf(v.z), fabsf(v.w)));
  ss = wave_sum(ss);
  ma = wave_max(ma);
  if (lane == 0) { sss[wv] = ss; sma[wv] = ma; }
  __syncthreads();
  const float tot_ss = (sss[0] + sss[1]) + (sss[2] + sss[3]);
  const float tot_ma = fmaxf(fmaxf(sma[0], sma[1]), fmaxf(sma[2], sma[3]));

  const float l2 = sqrtf(tot_ss);
  const float denom = fmaxf(l2, 1e-12f);
  const float inv = 0.03125f / denom;            // dim_scale / max(l2,eps)
  const float maxn = tot_ma * inv;
  const float scale = 127.0f / fmaxf(maxn, 1e-5f);
  const float f = inv * scale;

  float q0 = fminf(fmaxf(rintf(v.x * f), -128.f), 127.f);
  float q1 = fminf(fmaxf(rintf(v.y * f), -128.f), 127.f);
  float q2 = fminf(fmaxf(rintf(v.z * f), -128.f), 127.f);
  float q3 = fminf(fmaxf(rintf(v.w * f), -128.f), 127.f);

  ushort4 pk;
  pk.x = f32_to_bf16_exact(q0);
  pk.y = f32_to_bf16_exact(q1);
  pk.z = f32_to_bf16_exact(q2);
  pk.w = f32_to_bf16_exact(q3);
  *(ushort4*)(xq + (size_t)row * DIM + t * 4) = pk;
  if (t == 0) xscale[row] = scale;
}

// ---------------------------------------------------------------- GEMM
// out[m,n] = (sum_k xq[m,k]*wq[n,k] + bq[n]) / (w_scale * b_scale * xscale[m])
#define BM 128
#define BN 128
#define BK 64

__global__ __launch_bounds__(256) void gemm_bt(
    const unsigned short* __restrict__ Aq,  // [M, K] bf16 bits
    const unsigned short* __restrict__ Wq,  // [N, K] bf16 bits
    const float* __restrict__ bias,
    const float* __restrict__ red,
    const float* __restrict__ xscale,
    float* __restrict__ out) {
  __shared__ short As[BM * BK];  // row stride 64 bf16 = 128 B
  __shared__ short Bs[BN * BK];

  const int t = threadIdx.x;
  const int lane = t & 63;
  const int wv = t >> 6;
  const int quad = lane >> 4;
  const int r16 = lane & 15;
  const int wm = (wv >> 1) * 64;
  const int wn = (wv & 1) * 64;
  const int bm = blockIdx.y;
  const int bn = blockIdx.x;

  f32x4 acc[4][4] = {};

  const char* Ab = (const char*)(Aq + (size_t)bm * BM * DIM);
  const char* Bb = (const char*)(Wq + (size_t)bn * BN * DIM);
  char* AsB = (char*)As;
  char* BsB = (char*)Bs;

  const int srow = lane >> 3;        // row within 8-row chunk
  const int sbyte = (lane & 7) * 16; // byte offset within 128 B row

  for (int k0 = 0; k0 < DIM; k0 += BK) {
#pragma unroll
    for (int i = 0; i < 4; ++i) {
      const int c = wv * 4 + i;          // chunk 0..15, 8 rows each
      const int row = c * 8 + srow;
      __builtin_amdgcn_global_load_lds(
          (const __attribute__((address_space(1))) void*)(Ab + (size_t)row * (DIM * 2) + k0 * 2 + sbyte),
          (__attribute__((address_space(3))) void*)(AsB + c * 1024 + lane * 16),
          16, 0, 0);
      __builtin_amdgcn_global_load_lds(
          (const __attribute__((address_space(1))) void*)(Bb + (size_t)row * (DIM * 2) + k0 * 2 + sbyte),
          (__attribute__((address_space(3))) void*)(BsB + c * 1024 + lane * 16),
          16, 0, 0);
    }
    __syncthreads();
#pragma unroll
    for (int s = 0; s < 2; ++s) {
      short8 af[4], bf[4];
#pragma unroll
      for (int i = 0; i < 4; ++i) {
        af[i] = *(const short8*)(AsB + (wm + i * 16 + r16) * 128 + s * 64 + quad * 16);
        bf[i] = *(const short8*)(BsB + (wn + i * 16 + r16) * 128 + s * 64 + quad * 16);
      }
#pragma unroll
      for (int i = 0; i < 4; ++i)
#pragma unroll
        for (int j = 0; j < 4; ++j)
          acc[i][j] = __builtin_amdgcn_mfma_f32_16x16x32_bf16(af[i], bf[j], acc[i][j], 0, 0, 0);
    }
    __syncthreads();
  }

  // epilogue: dequant + ternary bias
  const float wscale = red[1] * INV_WN;
  const float bscale = red[3] * INV_BN;
  const float bmean = red[2] * INV_BN;
  const float wb = wscale * bscale;

  float rec[4][4];
#pragma unroll
  for (int i = 0; i < 4; ++i)
#pragma unroll
    for (int rr = 0; rr < 4; ++rr) {
      const int m = bm * BM + wm + i * 16 + quad * 4 + rr;
      rec[i][rr] = 1.0f / (wb * xscale[m]);
    }

#pragma unroll
  for (int j = 0; j < 4; ++j) {
    const int n = bn * BN + wn + j * 16 + r16;
    const float bd = bias[n] - bmean;
    const float bq = bd > 0.f ? 1.f : (bd < 0.f ? -1.f : 0.f);
#pragma unroll
    for (int i = 0; i < 4; ++i) {
      const int mg = bm * BM + wm + i * 16 + quad * 4;
      float* po = out + (size_t)mg * OUTF + n;
#pragma unroll
      for (int rr = 0; rr < 4; ++rr)
        po[(size_t)rr * OUTF] = (acc[i][j][rr] + bq) * rec[i][rr];
    }
  }
}

extern "C" void kernel_launch(void* const* d_in, const int* in_sizes, int n_in,
                              void* d_out, int out_size, void* d_ws, size_t ws_size,
                              hipStream_t stream) {
  const float* x = (const float*)d_in[0];
  const float* w = (const float*)d_in[1];
  const float* b = (const float*)d_in[2];
  float* out = (float*)d_out;
  char* ws = (char*)d_ws;

  float* red = (float*)ws;
  float* xscale = (float*)(ws + OFF_XSCALE);
  unsigned short* wq = (unsigned short*)(ws + OFF_WQ);
  unsigned short* xq = (unsigned short*)(ws + OFF_XQ);

  hipMemsetAsync(red, 0, 4 * sizeof(float), stream);
  reduce_wb<<<256, 256, 0, stream>>>(w, b, red);
  quant_w<<<1024, 256, 0, stream>>>(w, red, wq);
  quant_x<<<MROWS, 256, 0, stream>>>(x, xq, xscale);
  gemm_bt<<<dim3(OUTF / BN, MROWS / BM), 256, 0, stream>>>(xq, wq, b, red, xscale, out);
}

// Round 2
// 296.719 us; speedup vs baseline: 1.1515x; 1.1515x over previous
//
#include <hip/hip_runtime.h>
#include <cstdint>
#include <cstddef>

// BitLinear inference, round 2: i8 MFMA GEMM (2x bf16 rate, half staging
// bytes) + wave-per-row latency-optimized activation quant.
//
// ws layout (bytes):
//   [0       .. 16)        red[4] = {sum_w, sumabs_w, sum_b, sumabs_b}
//   [1024    .. 132096)    x_scale[32768] f32
//   [132096  .. 1180672)   w_q int8 [1024*1024]
//   [1180672 .. 34735104)  x_q int8 [32768*1024]

typedef __attribute__((ext_vector_type(4))) int int4v;

static constexpr int DIM = 1024;    // inner dim K
static constexpr int OUTF = 1024;   // output features N
static constexpr int MROWS = 32768; // B*S
static constexpr float INV_WN = 1.0f / (1024.0f * 1024.0f);
static constexpr float INV_BN = 1.0f / 1024.0f;

#define OFF_XSCALE 1024
#define OFF_WQ 132096
#define OFF_XQ 1180672

__device__ inline float wave_sum(float v) {
#pragma unroll
  for (int off = 32; off; off >>= 1) v += __shfl_xor(v, off);
  return v;
}
__device__ inline float wave_max(float v) {
#pragma unroll
  for (int off = 32; off; off >>= 1) v = fmaxf(v, __shfl_xor(v, off));
  return v;
}

// ---------------------------------------------------------------- reductions
__global__ __launch_bounds__(256) void reduce_wb(const float* __restrict__ w,
                                                 const float* __restrict__ b,
                                                 float* __restrict__ red) {
  __shared__ float ss[4], sa[4];
  const int t = threadIdx.x;
  const int lane = t & 63, wv = t >> 6;
  float s = 0.0f, a = 0.0f;
  const float4* w4 = (const float4*)w;
  const int idx = blockIdx.x * 256 + t;
#pragma unroll
  for (int i = 0; i < 4; ++i) {
    float4 v = w4[idx + i * 65536];
    s += (v.x + v.y) + (v.z + v.w);
    a += (fabsf(v.x) + fabsf(v.y)) + (fabsf(v.z) + fabsf(v.w));
  }
  s = wave_sum(s);
  a = wave_sum(a);
  if (lane == 0) { ss[wv] = s; sa[wv] = a; }
  __syncthreads();
  if (t == 0) atomicAdd(&red[0], (ss[0] + ss[1]) + (ss[2] + ss[3]));
  if (t == 1) atomicAdd(&red[1], (sa[0] + sa[1]) + (sa[2] + sa[3]));
  if (blockIdx.x == 0) {
    __syncthreads();  // block-uniform branch, safe
    float4 v = ((const float4*)b)[t];
    float s2 = (v.x + v.y) + (v.z + v.w);
    float a2 = (fabsf(v.x) + fabsf(v.y)) + (fabsf(v.z) + fabsf(v.w));
    s2 = wave_sum(s2);
    a2 = wave_max(a2) * 0.0f + wave_sum(a2);  // keep it simple: sum
    if (lane == 0) { ss[wv] = s2; sa[wv] = a2; }
    __syncthreads();
    if (t == 0) {
      red[2] = (ss[0] + ss[1]) + (ss[2] + ss[3]);
      red[3] = (sa[0] + sa[1]) + (sa[2] + sa[3]);
    }
  }
}

// ---------------------------------------------------------------- weight quant
__global__ __launch_bounds__(256) void quant_w(const float* __restrict__ w,
                                               const float* __restrict__ red,
                                               signed char* __restrict__ wq) {
  const float wmean = red[0] * INV_WN;
  const int idx = blockIdx.x * 256 + threadIdx.x;
  float4 v = ((const float4*)w)[idx];
  int q0, q1, q2, q3;
  float d;
  d = v.x - wmean; q0 = d > 0.f ? 1 : (d < 0.f ? -1 : 0);
  d = v.y - wmean; q1 = d > 0.f ? 1 : (d < 0.f ? -1 : 0);
  d = v.z - wmean; q2 = d > 0.f ? 1 : (d < 0.f ? -1 : 0);
  d = v.w - wmean; q3 = d > 0.f ? 1 : (d < 0.f ? -1 : 0);
  const int pk = (q0 & 0xff) | ((q1 & 0xff) << 8) | ((q2 & 0xff) << 16) | ((q3 & 0xff) << 24);
  ((int*)wq)[idx] = pk;
}

// ---------------------------------------------------------------- activation quant
// one wave per row; 16 floats/lane in registers; no __syncthreads
__global__ __launch_bounds__(256) void quant_x(const float* __restrict__ x,
                                               signed char* __restrict__ xq,
                                               float* __restrict__ xscale) {
  const int wv = threadIdx.x >> 6;
  const int lane = threadIdx.x & 63;
  const int row = blockIdx.x * 4 + wv;
  const float4* xr = (const float4*)(x + (size_t)row * DIM);
  float4 v[4];
  float ss = 0.0f, ma = 0.0f;
#pragma unroll
  for (int it = 0; it < 4; ++it) {
    v[it] = xr[it * 64 + lane];
    ss += v[it].x * v[it].x + v[it].y * v[it].y + v[it].z * v[it].z + v[it].w * v[it].w;
    ma = fmaxf(ma, fmaxf(fmaxf(fabsf(v[it].x), fabsf(v[it].y)),
                         fmaxf(fabsf(v[it].z), fabsf(v[it].w))));
  }
  ss = wave_sum(ss);
  ma = wave_max(ma);

  const float l2 = sqrtf(ss);
  const float inv = 0.03125f / fmaxf(l2, 1e-12f);       // dim_scale / max(l2,eps)
  const float scale = 127.0f / fmaxf(ma * inv, 1e-5f);  // per-token int8 scale
  const float f = inv * scale;

  int* outp = (int*)(xq + (size_t)row * DIM);
#pragma unroll
  for (int it = 0; it < 4; ++it) {
    const int q0 = (int)fminf(fmaxf(rintf(v[it].x * f), -128.f), 127.f);
    const int q1 = (int)fminf(fmaxf(rintf(v[it].y * f), -128.f), 127.f);
    const int q2 = (int)fminf(fmaxf(rintf(v[it].z * f), -128.f), 127.f);
    const int q3 = (int)fminf(fmaxf(rintf(v[it].w * f), -128.f), 127.f);
    outp[it * 64 + lane] =
        (q0 & 0xff) | ((q1 & 0xff) << 8) | ((q2 & 0xff) << 16) | ((q3 & 0xff) << 24);
  }
  if (lane == 0) xscale[row] = scale;
}

// ---------------------------------------------------------------- GEMM (i8)
// out[m,n] = (sum_k xq[m,k]*wq[n,k] + bq[n]) / (w_scale * b_scale * xscale[m])
#define BM 128
#define BN 128
#define BKB 128  // K-bytes per tile (i8 -> 128 elements)

__global__ __launch_bounds__(256) void gemm_i8(
    const signed char* __restrict__ Aq,  // [M, K] i8
    const signed char* __restrict__ Wq,  // [N, K] i8
    const float* __restrict__ bias,
    const float* __restrict__ red,
    const float* __restrict__ xscale,
    float* __restrict__ out) {
  __shared__ signed char As[BM * BKB];  // 16 KB, row stride 128 B
  __shared__ signed char Bs[BN * BKB];  // 16 KB

  const int t = threadIdx.x;
  const int lane = t & 63;
  const int wv = t >> 6;
  const int quad = lane >> 4;
  const int r16 = lane & 15;
  const int wm = (wv >> 1) * 64;
  const int wn = (wv & 1) * 64;
  const int bm = blockIdx.y;
  const int bn = blockIdx.x;

  int4v acc[4][4] = {};

  const char* Ab = (const char*)(Aq + (size_t)bm * BM * DIM);
  const char* Bb = (const char*)(Wq + (size_t)bn * BN * DIM);

  const int srow = lane >> 3;         // row within 8-row chunk
  const int sbyte = (lane & 7) * 16;  // byte offset within 128 B row

  for (int k0 = 0; k0 < DIM; k0 += BKB) {
#pragma unroll
    for (int i = 0; i < 4; ++i) {
      const int c = wv * 4 + i;  // chunk 0..15, 8 rows of 128 B each
      const int row = c * 8 + srow;
      __builtin_amdgcn_global_load_lds(
          (const __attribute__((address_space(1))) void*)(Ab + (size_t)row * DIM + k0 + sbyte),
          (__attribute__((address_space(3))) void*)((char*)As + c * 1024 + lane * 16),
          16, 0, 0);
      __builtin_amdgcn_global_load_lds(
          (const __attribute__((address_space(1))) void*)(Bb + (size_t)row * DIM + k0 + sbyte),
          (__attribute__((address_space(3))) void*)((char*)Bs + c * 1024 + lane * 16),
          16, 0, 0);
    }
    __syncthreads();
#pragma unroll
    for (int s = 0; s < 2; ++s) {  // two K=64 MFMA steps per 128-B tile row
      int4v af[4], bf[4];
#pragma unroll
      for (int i = 0; i < 4; ++i) {
        af[i] = *(const int4v*)(As + (wm + i * 16 + r16) * BKB + s * 64 + quad * 16);
        bf[i] = *(const int4v*)(Bs + (wn + i * 16 + r16) * BKB + s * 64 + quad * 16);
      }
#pragma unroll
      for (int i = 0; i < 4; ++i)
#pragma unroll
        for (int j = 0; j < 4; ++j)
          acc[i][j] = __builtin_amdgcn_mfma_i32_16x16x64_i8(af[i], bf[j], acc[i][j], 0, 0, 0);
    }
    __syncthreads();
  }

  // epilogue: ternary bias + dequant
  const float wscale = red[1] * INV_WN;
  const float bscale = red[3] * INV_BN;
  const float bmean = red[2] * INV_BN;
  const float wb = wscale * bscale;

  float rec[4][4];
#pragma unroll
  for (int i = 0; i < 4; ++i)
#pragma unroll
    for (int rr = 0; rr < 4; ++rr) {
      const int m = bm * BM + wm + i * 16 + quad * 4 + rr;
      rec[i][rr] = 1.0f / (wb * xscale[m]);
    }

#pragma unroll
  for (int j = 0; j < 4; ++j) {
    const int n = bn * BN + wn + j * 16 + r16;
    const float bd = bias[n] - bmean;
    const int bq = bd > 0.f ? 1 : (bd < 0.f ? -1 : 0);
#pragma unroll
    for (int i = 0; i < 4; ++i) {
      const int mg = bm * BM + wm + i * 16 + quad * 4;
      float* po = out + (size_t)mg * OUTF + n;
#pragma unroll
      for (int rr = 0; rr < 4; ++rr)
        po[(size_t)rr * OUTF] = (float)(acc[i][j][rr] + bq) * rec[i][rr];
    }
  }
}

extern "C" void kernel_launch(void* const* d_in, const int* in_sizes, int n_in,
                              void* d_out, int out_size, void* d_ws, size_t ws_size,
                              hipStream_t stream) {
  const float* x = (const float*)d_in[0];
  const float* w = (const float*)d_in[1];
  const float* b = (const float*)d_in[2];
  float* out = (float*)d_out;
  char* ws = (char*)d_ws;

  float* red = (float*)ws;
  float* xscale = (float*)(ws + OFF_XSCALE);
  signed char* wq = (signed char*)(ws + OFF_WQ);
  signed char* xq = (signed char*)(ws + OFF_XQ);

  hipMemsetAsync(red, 0, 4 * sizeof(float), stream);
  reduce_wb<<<256, 256, 0, stream>>>(w, b, red);
  quant_w<<<1024, 256, 0, stream>>>(w, red, wq);
  quant_x<<<MROWS / 4, 256, 0, stream>>>(x, xq, xscale);
  gemm_i8<<<dim3(OUTF / BN, MROWS / BM), 256, 0, stream>>>(xq, wq, b, red, xscale, out);
}